// Round 6
// baseline (1114.674 us; speedup 1.0000x reference)
//
#include <hip/hip_runtime.h>
#include <hip/hip_bf16.h>
#include <math.h>

#define N_Gc 50000
#define N_Dc 50000
#define DIM 64
#define RNK 32
#define NNZc 1600000
#define BSZ 2048
#define KEEPV (1.0f/0.9f)
#define INVT 5.0f
#define NBK 782      // (50000+63)/64 buckets of 64 rows
#define CPAD 16      // ints per cursor (one 64B line each)
#define NSL 24       // j-slices for lse grid
#define EPB 8000     // edges per block (hist2 + phaseA): NNZ/EPB = 200 blocks

typedef __attribute__((ext_vector_type(8))) short bfrag;
typedef __attribute__((ext_vector_type(4))) float f32x4;

__device__ inline ushort f2bf(float f) {
  union { float f; unsigned int u; } v; v.f = f;
  unsigned int r = (v.u + 0x7fffu + ((v.u >> 16) & 1u)) >> 16;
  return (ushort)r;
}
__device__ inline float bf2f(ushort u) {
  union { unsigned int i; float f; } v; v.i = ((unsigned int)u) << 16;
  return v.f;
}

// ---------------- hist2: LDS-privatized per-bucket counts ----------------
__global__ __launch_bounds__(256) void hist2_kernel(const int* __restrict__ rows, const int* __restrict__ cols,
                                                    int* __restrict__ bcnt_r, int* __restrict__ bcnt_c) {
  __shared__ int lh_r[NBK];
  __shared__ int lh_c[NBK];
  int t = threadIdx.x;
  for (int j = t; j < NBK; j += 256) { lh_r[j] = 0; lh_c[j] = 0; }
  __syncthreads();
  int e0 = blockIdx.x*EPB;
  for (int i = e0 + t; i < e0 + EPB; i += 256) {
    atomicAdd(&lh_r[rows[i] >> 6], 1);
    atomicAdd(&lh_c[cols[i] >> 6], 1);
  }
  __syncthreads();
  for (int j = t; j < NBK; j += 256) {
    int vr = lh_r[j]; if (vr) atomicAdd(&bcnt_r[j], vr);
    int vc = lh_c[j]; if (vc) atomicAdd(&bcnt_c[j], vc);
  }
}

// ---------------- cscan: prefix over bucket counts -> bucket bases + cursors ----------------
__global__ __launch_bounds__(1024) void cscan_kernel(const int* __restrict__ bcnt_r, const int* __restrict__ bcnt_c,
                                                     int* __restrict__ gcur_r, int* __restrict__ gcur_c,
                                                     int* __restrict__ bptr_r, int* __restrict__ bptr_c) {
  const int* cnt = blockIdx.x ? bcnt_c : bcnt_r;
  int* gcur = blockIdx.x ? gcur_c : gcur_r;
  int* bptr = blockIdx.x ? bptr_c : bptr_r;
  __shared__ int wsum[16];
  int t = threadIdx.x, lane = t & 63, w = t >> 6;
  int v = (t < NBK) ? cnt[t] : 0;
  int x = v;
  #pragma unroll
  for (int o = 1; o < 64; o <<= 1) { int y = __shfl_up(x, o); if (lane >= o) x += y; }
  if (lane == 63) wsum[w] = x;
  __syncthreads();
  if (t < 16) {
    int s = wsum[t];
    #pragma unroll
    for (int o = 1; o < 16; o <<= 1) { int y = __shfl_up(s, o); if (t >= o) s += y; }
    wsum[t] = s;
  }
  __syncthreads();
  int ex = ((w == 0) ? 0 : wsum[w-1]) + (x - v);
  if (t < NBK) { gcur[t*CPAD] = ex; bptr[t] = ex; }
  if (t == 0) bptr[NBK] = wsum[15];
}

// ---------------- phase A: block-local reserve + contiguous-run scatter ----------------
// record: x = other_id | (rel<<16) | (d0<<22) | (d1<<23) ; y = val bits
__global__ __launch_bounds__(256) void phaseA_kernel(const int* __restrict__ rows, const int* __restrict__ cols,
    const float* __restrict__ vals, const float* __restrict__ drop,
    int* __restrict__ gcur_r, int* __restrict__ gcur_c,
    uint2* __restrict__ stage_r, uint2* __restrict__ stage_c) {
  __shared__ int cnt_r[NBK], cnt_c[NBK];
  __shared__ int base_r[NBK], base_c[NBK];
  int t = threadIdx.x;
  for (int j = t; j < NBK; j += 256) { cnt_r[j] = 0; cnt_c[j] = 0; }
  __syncthreads();
  int e0 = blockIdx.x*EPB;
  // pass 1: count
  for (int i = e0 + t; i < e0 + EPB; i += 256) {
    atomicAdd(&cnt_r[rows[i] >> 6], 1);
    atomicAdd(&cnt_c[cols[i] >> 6], 1);
  }
  __syncthreads();
  // reserve contiguous runs, reset counters
  for (int j = t; j < NBK; j += 256) {
    int c = cnt_r[j]; base_r[j] = c ? atomicAdd(&gcur_r[j*CPAD], c) : 0; cnt_r[j] = 0;
    c = cnt_c[j];     base_c[j] = c ? atomicAdd(&gcur_c[j*CPAD], c) : 0; cnt_c[j] = 0;
  }
  __syncthreads();
  // pass 2: write records into reserved runs
  for (int i = e0 + t; i < e0 + EPB; i += 256) {
    int r = rows[i], c = cols[i];
    unsigned int vb = __float_as_uint(vals[i]);
    unsigned int dr0 = (drop[i] > 0.1f) ? (1u<<22) : 0u;
    unsigned int dc0 = (drop[(size_t)NNZc + i] > 0.1f) ? (1u<<22) : 0u;
    unsigned int dr1 = (drop[2*(size_t)NNZc + i] > 0.1f) ? (1u<<23) : 0u;
    unsigned int dc1 = (drop[3*(size_t)NNZc + i] > 0.1f) ? (1u<<23) : 0u;
    int br = r >> 6, bc = c >> 6;
    int p = base_r[br] + atomicAdd(&cnt_r[br], 1);
    stage_r[p] = make_uint2((unsigned int)c | ((unsigned int)(r & 63) << 16) | dr0 | dr1, vb);
    int q = base_c[bc] + atomicAdd(&cnt_c[bc], 1);
    stage_c[q] = make_uint2((unsigned int)r | ((unsigned int)(c & 63) << 16) | dc0 | dc1, vb);
  }
}

// ---------------- phase B: per-bucket row-count + prefix + place; writes CSR ptr ----------------
__global__ __launch_bounds__(256) void phaseB_kernel(const int* __restrict__ bptr, int* __restrict__ ptrout,
    const uint2* __restrict__ stage, ushort* __restrict__ fcol,
    float* __restrict__ fw0, float* __restrict__ fw1, int n) {
  __shared__ int cnt[64];
  __shared__ int pos[64];
  int t = threadIdx.x, b = blockIdx.x;
  int base_row = b*64;
  int base = bptr[b], endp = bptr[b+1];
  if (t < 64) cnt[t] = 0;
  __syncthreads();
  for (int k = base + t; k < endp; k += 256)
    atomicAdd(&cnt[(stage[k].x >> 16) & 63], 1);
  __syncthreads();
  if (t < 64) {
    int c = cnt[t], x = c;
    #pragma unroll
    for (int o = 1; o < 64; o <<= 1) { int y = __shfl_up(x, o); if (t >= o) x += y; }
    int excl = x - c;
    pos[t] = excl;
    int rr = base_row + t;
    if (rr <= n) ptrout[rr] = base + excl;
  }
  __syncthreads();
  for (int k = base + t; k < endp; k += 256) {
    uint2 rec = stage[k];
    int rel = (rec.x >> 16) & 63;
    int p = base + atomicAdd(&pos[rel], 1);
    float v = __uint_as_float(rec.y);
    fcol[p] = (ushort)(rec.x & 0xffffu);
    fw0[p] = (rec.x & (1u<<22)) ? v*KEEPV : 0.f;
    fw1[p] = (rec.x & (1u<<23)) ? v*KEEPV : 0.f;
  }
}

// ---------------- layer-0 SpMM: bf16 gather -> fp32 Z + bf16 Z copy ----------------
__global__ __launch_bounds__(256) void spmm_l0_kernel(const int* __restrict__ ptr,
    const ushort* __restrict__ fcol, const float* __restrict__ fw,
    const ushort* __restrict__ Eb, float* __restrict__ Z, ushort* __restrict__ Zb, int nrows) {
  int lane = threadIdx.x & 63;
  int row = blockIdx.x*4 + (threadIdx.x >> 6);
  if (row >= nrows) return;
  int k = ptr[row], end = ptr[row+1];
  float acc = 0.f;
  for (; k + 8 <= end; k += 8) {
    int cc[8]; float ww[8]; float gg[8];
    #pragma unroll
    for (int u = 0; u < 8; u++) { cc[u] = fcol[k+u]; ww[u] = fw[k+u]; }
    #pragma unroll
    for (int u = 0; u < 8; u++) gg[u] = bf2f(Eb[(size_t)cc[u]*DIM + lane]);
    #pragma unroll
    for (int u = 0; u < 8; u++) acc += ww[u]*gg[u];
  }
  for (; k < end; k++)
    acc += fw[k]*bf2f(Eb[(size_t)fcol[k]*DIM + lane]);
  size_t o = (size_t)row*DIM + lane;
  Z[o] = acc;
  Zb[o] = f2bf(acc);
}

// ---------------- layer-1 SpMM fused with E_sum: bf16 gather + fp32 adds -> bf16 out ----------------
__global__ __launch_bounds__(256) void spmm_l1_kernel(const int* __restrict__ ptr,
    const ushort* __restrict__ fcol, const float* __restrict__ fw,
    const ushort* __restrict__ Zb, const float* __restrict__ addA, const float* __restrict__ addB,
    ushort* __restrict__ Eout, int nrows) {
  int lane = threadIdx.x & 63;
  int row = blockIdx.x*4 + (threadIdx.x >> 6);
  if (row >= nrows) return;
  int k = ptr[row], end = ptr[row+1];
  float acc = 0.f;
  for (; k + 8 <= end; k += 8) {
    int cc[8]; float ww[8]; float gg[8];
    #pragma unroll
    for (int u = 0; u < 8; u++) { cc[u] = fcol[k+u]; ww[u] = fw[k+u]; }
    #pragma unroll
    for (int u = 0; u < 8; u++) gg[u] = bf2f(Zb[(size_t)cc[u]*DIM + lane]);
    #pragma unroll
    for (int u = 0; u < 8; u++) acc += ww[u]*gg[u];
  }
  for (; k < end; k++)
    acc += fw[k]*bf2f(Zb[(size_t)fcol[k]*DIM + lane]);
  size_t o = (size_t)row*DIM + lane;
  acc += addA[o] + addB[o];
  Eout[o] = f2bf(acc);
}

// ---------------- M[32][64] = vrow @ (E0 + Z0) ----------------
__global__ __launch_bounds__(256) void matred_kernel(const float* __restrict__ vrow,
    const float* __restrict__ E0, const float* __restrict__ Z0, float* __restrict__ M, int n) {
  __shared__ float part[RNK*DIM];
  int t = threadIdx.x, lane = t & 63, w = t >> 6;
  for (int i = t; i < RNK*DIM; i += 256) part[i] = 0.f;
  __syncthreads();
  int nw = gridDim.x*4;
  int wid = blockIdx.x*4 + w;
  int chunk = (n + nw - 1)/nw;
  int i0 = wid*chunk, i1 = min(n, i0 + chunk);
  float acc[RNK];
  #pragma unroll
  for (int r = 0; r < RNK; r++) acc[r] = 0.f;
  for (int i = i0; i < i1; i++) {
    float x = E0[(size_t)i*DIM + lane] + Z0[(size_t)i*DIM + lane];
    #pragma unroll
    for (int r = 0; r < RNK; r++) acc[r] += vrow[(size_t)r*n + i]*x;
  }
  #pragma unroll
  for (int r = 0; r < RNK; r++) atomicAdd(&part[r*DIM + lane], acc[r]);
  __syncthreads();
  for (int i = t; i < RNK*DIM; i += 256) atomicAdd(&M[i], part[i]);
}

// ---------------- G rows at sampled ids (fp32 + bf16 out) ----------------
__global__ __launch_bounds__(256) void gsmall_kernel(const int* __restrict__ ids,
    const float* __restrict__ E0, const float* __restrict__ mul, const float* __restrict__ M,
    float* __restrict__ out, ushort* __restrict__ outb) {
  __shared__ float Ms[RNK*DIM];
  int t = threadIdx.x;
  for (int i = t; i < RNK*DIM; i += 256) Ms[i] = M[i];
  __syncthreads();
  int b = blockIdx.x*4 + (t >> 6), lane = t & 63;
  int u = ids[b];
  float a = E0[(size_t)u*DIM + lane];
  #pragma unroll
  for (int r = 0; r < RNK; r++) a += mul[(size_t)u*RNK + r]*Ms[r*DIM + lane];
  out[(size_t)b*DIM + lane] = a;
  outb[(size_t)b*DIM + lane] = f2bf(a);
}

// ---------------- fp32 -> bf16 conversion fused with sum-of-squares ----------------
__global__ __launch_bounds__(256) void convsq_kernel(const float4* __restrict__ in,
    ushort4* __restrict__ out, int n4, float* __restrict__ acc) {
  int i = blockIdx.x*256 + threadIdx.x;
  float s = 0.f;
  if (i < n4) {
    float4 v = in[i];
    ushort4 o;
    o.x = f2bf(v.x); o.y = f2bf(v.y); o.z = f2bf(v.z); o.w = f2bf(v.w);
    out[i] = o;
    s = v.x*v.x + v.y*v.y + v.z*v.z + v.w*v.w;
  }
  #pragma unroll
  for (int o = 32; o > 0; o >>= 1) s += __shfl_xor(s, o);
  if ((threadIdx.x & 63) == 0) atomicAdd(acc, s);
}

// ---------------- bf16 MFMA fused GEMM + exp + row-sum ----------------
__global__ __launch_bounds__(256) void lse_mfma_kernel(const ushort* __restrict__ A,
    const ushort* __restrict__ X, int nj, float* __restrict__ sumexp) {
  __shared__ __align__(16) ushort Xs[64*68];
  int t = threadIdx.x, lane = t & 63, w = t >> 6;
  int bt = blockIdx.x & 31, js = blockIdx.x >> 5;
  int b0 = bt*64;
  int m = lane & 15, q = lane >> 4;
  const ushort* Arow = A + (size_t)(b0 + w*16 + m)*DIM + q*8;
  bfrag a0 = *(const bfrag*)(Arow);
  bfrag a1 = *(const bfrag*)(Arow + 32);
  float rs0 = 0.f, rs1 = 0.f, rs2 = 0.f, rs3 = 0.f;
  int njt = (nj + 63) >> 6;
  for (int jt = js; jt < njt; jt += NSL) {
    int j0 = jt << 6;
    __syncthreads();
    for (int c = t; c < 512; c += 256) {
      int r = c >> 3, k8 = (c & 7) << 3;
      int j = j0 + r;
      ushort4 v0 = {0,0,0,0}, v1 = {0,0,0,0};
      if (j < nj) {
        const ushort4* src = (const ushort4*)(X + (size_t)j*DIM + k8);
        v0 = src[0]; v1 = src[1];
      }
      *(ushort4*)&Xs[r*68 + k8]     = v0;
      *(ushort4*)&Xs[r*68 + k8 + 4] = v1;
    }
    __syncthreads();
    #pragma unroll
    for (int jq = 0; jq < 4; jq++) {
      int jr = jq*16 + m;
      union { bfrag f; uint2 u2[2]; } B0, B1;
      B0.u2[0] = *(const uint2*)&Xs[jr*68 + q*8];
      B0.u2[1] = *(const uint2*)&Xs[jr*68 + q*8 + 4];
      B1.u2[0] = *(const uint2*)&Xs[jr*68 + 32 + q*8];
      B1.u2[1] = *(const uint2*)&Xs[jr*68 + 32 + q*8 + 4];
      f32x4 acc = {0.f, 0.f, 0.f, 0.f};
      acc = __builtin_amdgcn_mfma_f32_16x16x32_bf16(a0, B0.f, acc, 0, 0, 0);
      acc = __builtin_amdgcn_mfma_f32_16x16x32_bf16(a1, B1.f, acc, 0, 0, 0);
      int jg = j0 + jr;
      if (jg < nj) {
        rs0 += __expf(acc[0]*INVT);
        rs1 += __expf(acc[1]*INVT);
        rs2 += __expf(acc[2]*INVT);
        rs3 += __expf(acc[3]*INVT);
      }
    }
  }
  #pragma unroll
  for (int o = 1; o < 16; o <<= 1) {
    rs0 += __shfl_xor(rs0, o);
    rs1 += __shfl_xor(rs1, o);
    rs2 += __shfl_xor(rs2, o);
    rs3 += __shfl_xor(rs3, o);
  }
  if (m == 0) {
    float* dst = &sumexp[b0 + w*16 + q*4];
    atomicAdd(&dst[0], rs0);
    atomicAdd(&dst[1], rs1);
    atomicAdd(&dst[2], rs2);
    atomicAdd(&dst[3], rs3);
  }
}

// ---------------- per-sample terms (bf16 E_sum tables) ----------------
__global__ __launch_bounds__(256) void perb_kernel(const int* __restrict__ uids, const int* __restrict__ iids,
    const int* __restrict__ pos, const int* __restrict__ neg,
    const float* __restrict__ Ggu, const float* __restrict__ Gdi,
    const ushort* __restrict__ Egs_b, const ushort* __restrict__ Eds_b,
    const float* __restrict__ seg, const float* __restrict__ sed,
    float* __restrict__ accs) {
  int t = threadIdx.x, lane = t & 63;
  int b = blockIdx.x*4 + (t >> 6);
  int u = uids[b], it = iids[b], p = pos[b], ng = neg[b];
  float egu = bf2f(Egs_b[(size_t)u*DIM + lane]);
  float d1 = Ggu[(size_t)b*DIM + lane]*egu;
  float d2 = Gdi[(size_t)b*DIM + lane]*bf2f(Eds_b[(size_t)it*DIM + lane]);
  float d3 = egu*bf2f(Eds_b[(size_t)p*DIM + lane]);
  float d4 = egu*bf2f(Eds_b[(size_t)ng*DIM + lane]);
  #pragma unroll
  for (int o = 32; o > 0; o >>= 1) {
    d1 += __shfl_xor(d1, o);
    d2 += __shfl_xor(d2, o);
    d3 += __shfl_xor(d3, o);
    d4 += __shfl_xor(d4, o);
  }
  if (lane == 0) {
    float pterm = fminf(fmaxf(d1*INVT, -5.f), 5.f) + fminf(fmaxf(d2*INVT, -5.f), 5.f);
    float diff = d3 - d4;
    float lr = log1pf(expf(-diff));
    float lg = logf(seg[b] + 1e-8f) + logf(sed[b] + 1e-8f);
    atomicAdd(&accs[0], pterm);
    atomicAdd(&accs[1], lr);
    atomicAdd(&accs[2], lg);
  }
}

__global__ void final_kernel(const float* __restrict__ accs, float* __restrict__ out) {
  float posm = accs[0]*(1.f/BSZ);
  float lr   = accs[1]*(1.f/BSZ);
  float negm = accs[2]*(1.f/BSZ);
  float reg  = 1e-7f*accs[3];
  float l1ls = 0.2f*(negm - posm);
  out[0] = lr + l1ls + reg;
  out[1] = lr;
  out[2] = l1ls;
}

extern "C" void kernel_launch(void* const* d_in, const int* in_sizes, int n_in,
                              void* d_out, int out_size, void* d_ws, size_t ws_size,
                              hipStream_t stream) {
  (void)in_sizes; (void)n_in; (void)out_size;
  const int*   uids = (const int*)d_in[0];
  const int*   iids = (const int*)d_in[1];
  const int*   pos  = (const int*)d_in[2];
  const int*   neg  = (const int*)d_in[3];
  const float* Eg0  = (const float*)d_in[4];
  const float* Ed0  = (const float*)d_in[5];
  const int*   rows = (const int*)d_in[6];
  const int*   cols = (const int*)d_in[7];
  const float* vals = (const float*)d_in[8];
  const float* gms  = (const float*)d_in[9];
  const float* vms  = (const float*)d_in[10];
  const float* ut   = (const float*)d_in[11];
  const float* vt   = (const float*)d_in[12];
  const float* drop = (const float*)d_in[13];
  float* out = (float*)d_out;

  float* ws = (float*)d_ws;
  const size_t ED = (size_t)N_Gc*DIM;  // 3.2M
  float* Zg0  = ws;            // [ED] fp32 Z layer0 r-side; earlier: stage_r (NNZ uint2 = ED floats)
  float* Zd0  = Zg0 + ED;      // [ED] fp32 Z layer0 c-side
  float* REG1 = Zd0 + ED;      // [ED] : stage_c -> (Eg0_b,Ed0_b) -> (Egs_b,Eds_b)
  float* REG2 = REG1 + ED;     // [ED] : (Zg0_b, Zd0_b)
  int* ptr_r = (int*)(REG2 + ED);
  int* ptr_c = ptr_r + (N_Gc + 1);
  int* bcnt_r = ptr_c + (N_Dc + 1);        // zeroed zone A
  int* bcnt_c = bcnt_r + NBK;              // zone A end
  int* bptr_r = bcnt_c + NBK;
  int* bptr_c = bptr_r + (NBK + 1);
  int* gcur_r = bptr_c + (NBK + 1);
  int* gcur_c = gcur_r + NBK*CPAD;
  ushort* fcol_r = (ushort*)(gcur_c + NBK*CPAD);
  float* fw_r0  = (float*)(fcol_r + NNZc);
  float* fw_r1  = fw_r0 + NNZc;
  ushort* fcol_c = (ushort*)(fw_r1 + NNZc);
  float* fw_c0  = (float*)(fcol_c + NNZc);
  float* fw_c1  = fw_c0 + NNZc;
  float* Ggu = fw_c1 + NNZc;
  float* Gdi = Ggu + (size_t)BSZ*DIM;
  ushort* Ggu_b = (ushort*)(Gdi + (size_t)BSZ*DIM);
  ushort* Gdi_b = Ggu_b + (size_t)BSZ*DIM;
  float* Mg  = (float*)(Gdi_b + (size_t)BSZ*DIM);  // zeroed zone B
  float* Md  = Mg + RNK*DIM;
  float* seg = Md + RNK*DIM;
  float* sed = seg + BSZ;
  float* accs = sed + BSZ;              // 16 floats

  // overlays (lifetimes are disjoint on the serial stream):
  uint2* stage_r = (uint2*)Zg0;                 // phaseA..phaseB
  uint2* stage_c = (uint2*)REG1;                // phaseA..phaseB
  ushort* Eg0_b = (ushort*)REG1;                // conv..layer0
  ushort* Ed0_b = Eg0_b + ED;
  ushort* Egs_b = (ushort*)REG1;                // layer1..end (overwrites dead Eg0_b)
  ushort* Eds_b = Egs_b + ED;
  ushort* Zg0_b = (ushort*)REG2;                // layer0..layer1
  ushort* Zd0_b = Zg0_b + ED;

  size_t need = ((char*)(accs + 16)) - ((char*)d_ws);
  if (ws_size < need) return;

  hipMemsetAsync(bcnt_r, 0, sizeof(int)*(2*NBK), stream);
  hipMemsetAsync(Mg, 0, sizeof(float)*(2*RNK*DIM + 2*BSZ + 16), stream);

  hist2_kernel<<<NNZc/EPB, 256, 0, stream>>>(rows, cols, bcnt_r, bcnt_c);
  cscan_kernel<<<2, 1024, 0, stream>>>(bcnt_r, bcnt_c, gcur_r, gcur_c, bptr_r, bptr_c);
  phaseA_kernel<<<NNZc/EPB, 256, 0, stream>>>(rows, cols, vals, drop, gcur_r, gcur_c, stage_r, stage_c);
  phaseB_kernel<<<NBK, 256, 0, stream>>>(bptr_r, ptr_r, stage_r, fcol_r, fw_r0, fw_r1, N_Gc);
  phaseB_kernel<<<NBK, 256, 0, stream>>>(bptr_c, ptr_c, stage_c, fcol_c, fw_c0, fw_c1, N_Dc);

  // bf16 copies of the layer-0 gather tables (stage_c now dead) + fused L2-reg sum-of-squares
  int n4 = (int)(ED/4);
  convsq_kernel<<<(n4 + 255)/256, 256, 0, stream>>>((const float4*)Eg0, (ushort4*)Eg0_b, n4, accs + 3);
  convsq_kernel<<<(n4 + 255)/256, 256, 0, stream>>>((const float4*)Ed0, (ushort4*)Ed0_b, n4, accs + 3);

  int spmm_blocks = (N_Gc + 3)/4;
  // layer 0: Zg0 = A0 @ Ed0 ; Zd0 = A0^T @ Eg0  (bf16 gathers, fp32 + bf16 outputs)
  spmm_l0_kernel<<<spmm_blocks, 256, 0, stream>>>(ptr_r, fcol_r, fw_r0, Ed0_b, Zg0, Zg0_b, N_Gc);
  spmm_l0_kernel<<<spmm_blocks, 256, 0, stream>>>(ptr_c, fcol_c, fw_c0, Eg0_b, Zd0, Zd0_b, N_Dc);
  // layer 1 fused: Egs = Eg0 + Zg0 + A1 @ Zd0 -> bf16 only ; Eds likewise
  spmm_l1_kernel<<<spmm_blocks, 256, 0, stream>>>(ptr_r, fcol_r, fw_r1, Zd0_b, Eg0, Zg0, Egs_b, N_Gc);
  spmm_l1_kernel<<<spmm_blocks, 256, 0, stream>>>(ptr_c, fcol_c, fw_c1, Zg0_b, Ed0, Zd0, Eds_b, N_Dc);

  // Mg = vt @ (Ed0 + Zd0) ; Md = ut @ (Eg0 + Zg0)
  matred_kernel<<<64, 256, 0, stream>>>(vt, Ed0, Zd0, Mg, N_Dc);
  matred_kernel<<<64, 256, 0, stream>>>(ut, Eg0, Zg0, Md, N_Gc);

  gsmall_kernel<<<BSZ/4, 256, 0, stream>>>(uids, Eg0, gms, Mg, Ggu, Ggu_b);
  gsmall_kernel<<<BSZ/4, 256, 0, stream>>>(iids, Ed0, vms, Md, Gdi, Gdi_b);

  lse_mfma_kernel<<<32*NSL, 256, 0, stream>>>(Ggu_b, Egs_b, N_Gc, seg);
  lse_mfma_kernel<<<32*NSL, 256, 0, stream>>>(Gdi_b, Eds_b, N_Dc, sed);

  perb_kernel<<<BSZ/4, 256, 0, stream>>>(uids, iids, pos, neg, Ggu, Gdi, Egs_b, Eds_b, seg, sed, accs);
  final_kernel<<<1, 1, 0, stream>>>(accs, out);
}

// Round 7
// 751.177 us; speedup vs baseline: 1.4839x; 1.4839x over previous
//
#include <hip/hip_runtime.h>
#include <hip/hip_bf16.h>
#include <math.h>

#define N_Gc 50000
#define N_Dc 50000
#define DIM 64
#define RNK 32
#define NNZc 1600000
#define BSZ 2048
#define KEEPV (1.0f/0.9f)
#define INVT 5.0f
#define NBK 782      // (50000+63)/64 buckets of 64 rows
#define CPAD 16      // ints per cursor (one 64B line each)
#define NSL 24       // j-slices for lse grid
#define EPB 8000     // edges per block (hist2 + phaseA): NNZ/EPB = 200 blocks

typedef __attribute__((ext_vector_type(8))) short bfrag;
typedef __attribute__((ext_vector_type(4))) float f32x4;

__device__ inline ushort f2bf(float f) {
  union { float f; unsigned int u; } v; v.f = f;
  unsigned int r = (v.u + 0x7fffu + ((v.u >> 16) & 1u)) >> 16;
  return (ushort)r;
}
__device__ inline float bf2f(ushort u) {
  union { unsigned int i; float f; } v; v.i = ((unsigned int)u) << 16;
  return v.f;
}

// ---------------- hist2: LDS-privatized per-bucket counts ----------------
__global__ __launch_bounds__(256) void hist2_kernel(const int* __restrict__ rows, const int* __restrict__ cols,
                                                    int* __restrict__ bcnt_r, int* __restrict__ bcnt_c) {
  __shared__ int lh_r[NBK];
  __shared__ int lh_c[NBK];
  int t = threadIdx.x;
  for (int j = t; j < NBK; j += 256) { lh_r[j] = 0; lh_c[j] = 0; }
  __syncthreads();
  int e0 = blockIdx.x*EPB;
  for (int i = e0 + t; i < e0 + EPB; i += 256) {
    atomicAdd(&lh_r[rows[i] >> 6], 1);
    atomicAdd(&lh_c[cols[i] >> 6], 1);
  }
  __syncthreads();
  for (int j = t; j < NBK; j += 256) {
    int vr = lh_r[j]; if (vr) atomicAdd(&bcnt_r[j], vr);
    int vc = lh_c[j]; if (vc) atomicAdd(&bcnt_c[j], vc);
  }
}

// ---------------- cscan: prefix over bucket counts -> bucket bases + cursors ----------------
__global__ __launch_bounds__(1024) void cscan_kernel(const int* __restrict__ bcnt_r, const int* __restrict__ bcnt_c,
                                                     int* __restrict__ gcur_r, int* __restrict__ gcur_c,
                                                     int* __restrict__ bptr_r, int* __restrict__ bptr_c) {
  const int* cnt = blockIdx.x ? bcnt_c : bcnt_r;
  int* gcur = blockIdx.x ? gcur_c : gcur_r;
  int* bptr = blockIdx.x ? bptr_c : bptr_r;
  __shared__ int wsum[16];
  int t = threadIdx.x, lane = t & 63, w = t >> 6;
  int v = (t < NBK) ? cnt[t] : 0;
  int x = v;
  #pragma unroll
  for (int o = 1; o < 64; o <<= 1) { int y = __shfl_up(x, o); if (lane >= o) x += y; }
  if (lane == 63) wsum[w] = x;
  __syncthreads();
  if (t < 16) {
    int s = wsum[t];
    #pragma unroll
    for (int o = 1; o < 16; o <<= 1) { int y = __shfl_up(s, o); if (t >= o) s += y; }
    wsum[t] = s;
  }
  __syncthreads();
  int ex = ((w == 0) ? 0 : wsum[w-1]) + (x - v);
  if (t < NBK) { gcur[t*CPAD] = ex; bptr[t] = ex; }
  if (t == 0) bptr[NBK] = wsum[15];
}

// ---------------- phase A: block-local reserve + contiguous-run scatter ----------------
__global__ __launch_bounds__(256) void phaseA_kernel(const int* __restrict__ rows, const int* __restrict__ cols,
    const float* __restrict__ vals, const float* __restrict__ drop,
    int* __restrict__ gcur_r, int* __restrict__ gcur_c,
    uint2* __restrict__ stage_r, uint2* __restrict__ stage_c) {
  __shared__ int cnt_r[NBK], cnt_c[NBK];
  __shared__ int base_r[NBK], base_c[NBK];
  int t = threadIdx.x;
  for (int j = t; j < NBK; j += 256) { cnt_r[j] = 0; cnt_c[j] = 0; }
  __syncthreads();
  int e0 = blockIdx.x*EPB;
  for (int i = e0 + t; i < e0 + EPB; i += 256) {
    atomicAdd(&cnt_r[rows[i] >> 6], 1);
    atomicAdd(&cnt_c[cols[i] >> 6], 1);
  }
  __syncthreads();
  for (int j = t; j < NBK; j += 256) {
    int c = cnt_r[j]; base_r[j] = c ? atomicAdd(&gcur_r[j*CPAD], c) : 0; cnt_r[j] = 0;
    c = cnt_c[j];     base_c[j] = c ? atomicAdd(&gcur_c[j*CPAD], c) : 0; cnt_c[j] = 0;
  }
  __syncthreads();
  for (int i = e0 + t; i < e0 + EPB; i += 256) {
    int r = rows[i], c = cols[i];
    unsigned int vb = __float_as_uint(vals[i]);
    unsigned int dr0 = (drop[i] > 0.1f) ? (1u<<22) : 0u;
    unsigned int dc0 = (drop[(size_t)NNZc + i] > 0.1f) ? (1u<<22) : 0u;
    unsigned int dr1 = (drop[2*(size_t)NNZc + i] > 0.1f) ? (1u<<23) : 0u;
    unsigned int dc1 = (drop[3*(size_t)NNZc + i] > 0.1f) ? (1u<<23) : 0u;
    int br = r >> 6, bc = c >> 6;
    int p = base_r[br] + atomicAdd(&cnt_r[br], 1);
    stage_r[p] = make_uint2((unsigned int)c | ((unsigned int)(r & 63) << 16) | dr0 | dr1, vb);
    int q = base_c[bc] + atomicAdd(&cnt_c[bc], 1);
    stage_c[q] = make_uint2((unsigned int)r | ((unsigned int)(c & 63) << 16) | dc0 | dc1, vb);
  }
}

// ---------------- phase B: per-bucket row-count + prefix + place; writes CSR ptr ----------------
__global__ __launch_bounds__(256) void phaseB_kernel(const int* __restrict__ bptr, int* __restrict__ ptrout,
    const uint2* __restrict__ stage, ushort* __restrict__ fcol,
    float* __restrict__ fw0, float* __restrict__ fw1, int n) {
  __shared__ int cnt[64];
  __shared__ int pos[64];
  int t = threadIdx.x, b = blockIdx.x;
  int base_row = b*64;
  int base = bptr[b], endp = bptr[b+1];
  if (t < 64) cnt[t] = 0;
  __syncthreads();
  for (int k = base + t; k < endp; k += 256)
    atomicAdd(&cnt[(stage[k].x >> 16) & 63], 1);
  __syncthreads();
  if (t < 64) {
    int c = cnt[t], x = c;
    #pragma unroll
    for (int o = 1; o < 64; o <<= 1) { int y = __shfl_up(x, o); if (t >= o) x += y; }
    int excl = x - c;
    pos[t] = excl;
    int rr = base_row + t;
    if (rr <= n) ptrout[rr] = base + excl;
  }
  __syncthreads();
  for (int k = base + t; k < endp; k += 256) {
    uint2 rec = stage[k];
    int rel = (rec.x >> 16) & 63;
    int p = base + atomicAdd(&pos[rel], 1);
    float v = __uint_as_float(rec.y);
    fcol[p] = (ushort)(rec.x & 0xffffu);
    fw0[p] = (rec.x & (1u<<22)) ? v*KEEPV : 0.f;
    fw1[p] = (rec.x & (1u<<23)) ? v*KEEPV : 0.f;
  }
}

// ---------------- layer-0 SpMM: bf16 gather -> fp32 Z + bf16 Z copy ----------------
__global__ __launch_bounds__(256) void spmm_l0_kernel(const int* __restrict__ ptr,
    const ushort* __restrict__ fcol, const float* __restrict__ fw,
    const ushort* __restrict__ Eb, float* __restrict__ Z, ushort* __restrict__ Zb, int nrows) {
  int lane = threadIdx.x & 63;
  int row = blockIdx.x*4 + (threadIdx.x >> 6);
  if (row >= nrows) return;
  int k = ptr[row], end = ptr[row+1];
  float acc = 0.f;
  for (; k + 8 <= end; k += 8) {
    int cc[8]; float ww[8]; float gg[8];
    #pragma unroll
    for (int u = 0; u < 8; u++) { cc[u] = fcol[k+u]; ww[u] = fw[k+u]; }
    #pragma unroll
    for (int u = 0; u < 8; u++) gg[u] = bf2f(Eb[(size_t)cc[u]*DIM + lane]);
    #pragma unroll
    for (int u = 0; u < 8; u++) acc += ww[u]*gg[u];
  }
  for (; k < end; k++)
    acc += fw[k]*bf2f(Eb[(size_t)fcol[k]*DIM + lane]);
  size_t o = (size_t)row*DIM + lane;
  Z[o] = acc;
  Zb[o] = f2bf(acc);
}

// ---------------- layer-1 SpMM fused with E_sum: bf16 gather + fp32 adds -> bf16 out ----------------
__global__ __launch_bounds__(256) void spmm_l1_kernel(const int* __restrict__ ptr,
    const ushort* __restrict__ fcol, const float* __restrict__ fw,
    const ushort* __restrict__ Zb, const float* __restrict__ addA, const float* __restrict__ addB,
    ushort* __restrict__ Eout, int nrows) {
  int lane = threadIdx.x & 63;
  int row = blockIdx.x*4 + (threadIdx.x >> 6);
  if (row >= nrows) return;
  int k = ptr[row], end = ptr[row+1];
  float acc = 0.f;
  for (; k + 8 <= end; k += 8) {
    int cc[8]; float ww[8]; float gg[8];
    #pragma unroll
    for (int u = 0; u < 8; u++) { cc[u] = fcol[k+u]; ww[u] = fw[k+u]; }
    #pragma unroll
    for (int u = 0; u < 8; u++) gg[u] = bf2f(Zb[(size_t)cc[u]*DIM + lane]);
    #pragma unroll
    for (int u = 0; u < 8; u++) acc += ww[u]*gg[u];
  }
  for (; k < end; k++)
    acc += fw[k]*bf2f(Zb[(size_t)fcol[k]*DIM + lane]);
  size_t o = (size_t)row*DIM + lane;
  acc += addA[o] + addB[o];
  Eout[o] = f2bf(acc);
}

// ---------------- M[32][64] = vrow @ (E0 + Z0) ----------------
__global__ __launch_bounds__(256) void matred_kernel(const float* __restrict__ vrow,
    const float* __restrict__ E0, const float* __restrict__ Z0, float* __restrict__ M, int n) {
  __shared__ float part[RNK*DIM];
  int t = threadIdx.x, lane = t & 63, w = t >> 6;
  for (int i = t; i < RNK*DIM; i += 256) part[i] = 0.f;
  __syncthreads();
  int nw = gridDim.x*4;
  int wid = blockIdx.x*4 + w;
  int chunk = (n + nw - 1)/nw;
  int i0 = wid*chunk, i1 = min(n, i0 + chunk);
  float acc[RNK];
  #pragma unroll
  for (int r = 0; r < RNK; r++) acc[r] = 0.f;
  for (int i = i0; i < i1; i++) {
    float x = E0[(size_t)i*DIM + lane] + Z0[(size_t)i*DIM + lane];
    #pragma unroll
    for (int r = 0; r < RNK; r++) acc[r] += vrow[(size_t)r*n + i]*x;
  }
  #pragma unroll
  for (int r = 0; r < RNK; r++) atomicAdd(&part[r*DIM + lane], acc[r]);
  __syncthreads();
  for (int i = t; i < RNK*DIM; i += 256) atomicAdd(&M[i], part[i]);
}

// ---------------- G rows at sampled ids (fp32 + bf16 out) ----------------
__global__ __launch_bounds__(256) void gsmall_kernel(const int* __restrict__ ids,
    const float* __restrict__ E0, const float* __restrict__ mul, const float* __restrict__ M,
    float* __restrict__ out, ushort* __restrict__ outb) {
  __shared__ float Ms[RNK*DIM];
  int t = threadIdx.x;
  for (int i = t; i < RNK*DIM; i += 256) Ms[i] = M[i];
  __syncthreads();
  int b = blockIdx.x*4 + (t >> 6), lane = t & 63;
  int u = ids[b];
  float a = E0[(size_t)u*DIM + lane];
  #pragma unroll
  for (int r = 0; r < RNK; r++) a += mul[(size_t)u*RNK + r]*Ms[r*DIM + lane];
  out[(size_t)b*DIM + lane] = a;
  outb[(size_t)b*DIM + lane] = f2bf(a);
}

// ---------------- fp32 -> bf16 conversion fused with sum-of-squares (1 atomic/block) ----------------
__global__ __launch_bounds__(256) void convsq_kernel(const float4* __restrict__ in,
    ushort4* __restrict__ out, int n4, float* __restrict__ acc) {
  __shared__ float ls[4];
  int t = threadIdx.x;
  int idx = blockIdx.x*256 + t;
  int stride = gridDim.x*256;
  float s = 0.f;
  for (int i = idx; i < n4; i += stride) {
    float4 v = in[i];
    ushort4 o;
    o.x = f2bf(v.x); o.y = f2bf(v.y); o.z = f2bf(v.z); o.w = f2bf(v.w);
    out[i] = o;
    s += v.x*v.x + v.y*v.y + v.z*v.z + v.w*v.w;
  }
  #pragma unroll
  for (int o = 32; o > 0; o >>= 1) s += __shfl_xor(s, o);
  if ((t & 63) == 0) ls[t >> 6] = s;
  __syncthreads();
  if (t == 0) atomicAdd(acc, ls[0] + ls[1] + ls[2] + ls[3]);
}

// ---------------- bf16 MFMA fused GEMM + exp + row-sum ----------------
__global__ __launch_bounds__(256) void lse_mfma_kernel(const ushort* __restrict__ A,
    const ushort* __restrict__ X, int nj, float* __restrict__ sumexp) {
  __shared__ __align__(16) ushort Xs[64*68];
  int t = threadIdx.x, lane = t & 63, w = t >> 6;
  int bt = blockIdx.x & 31, js = blockIdx.x >> 5;
  int b0 = bt*64;
  int m = lane & 15, q = lane >> 4;
  const ushort* Arow = A + (size_t)(b0 + w*16 + m)*DIM + q*8;
  bfrag a0 = *(const bfrag*)(Arow);
  bfrag a1 = *(const bfrag*)(Arow + 32);
  float rs0 = 0.f, rs1 = 0.f, rs2 = 0.f, rs3 = 0.f;
  int njt = (nj + 63) >> 6;
  for (int jt = js; jt < njt; jt += NSL) {
    int j0 = jt << 6;
    __syncthreads();
    for (int c = t; c < 512; c += 256) {
      int r = c >> 3, k8 = (c & 7) << 3;
      int j = j0 + r;
      ushort4 v0 = {0,0,0,0}, v1 = {0,0,0,0};
      if (j < nj) {
        const ushort4* src = (const ushort4*)(X + (size_t)j*DIM + k8);
        v0 = src[0]; v1 = src[1];
      }
      *(ushort4*)&Xs[r*68 + k8]     = v0;
      *(ushort4*)&Xs[r*68 + k8 + 4] = v1;
    }
    __syncthreads();
    #pragma unroll
    for (int jq = 0; jq < 4; jq++) {
      int jr = jq*16 + m;
      union { bfrag f; uint2 u2[2]; } B0, B1;
      B0.u2[0] = *(const uint2*)&Xs[jr*68 + q*8];
      B0.u2[1] = *(const uint2*)&Xs[jr*68 + q*8 + 4];
      B1.u2[0] = *(const uint2*)&Xs[jr*68 + 32 + q*8];
      B1.u2[1] = *(const uint2*)&Xs[jr*68 + 32 + q*8 + 4];
      f32x4 acc = {0.f, 0.f, 0.f, 0.f};
      acc = __builtin_amdgcn_mfma_f32_16x16x32_bf16(a0, B0.f, acc, 0, 0, 0);
      acc = __builtin_amdgcn_mfma_f32_16x16x32_bf16(a1, B1.f, acc, 0, 0, 0);
      int jg = j0 + jr;
      if (jg < nj) {
        rs0 += __expf(acc[0]*INVT);
        rs1 += __expf(acc[1]*INVT);
        rs2 += __expf(acc[2]*INVT);
        rs3 += __expf(acc[3]*INVT);
      }
    }
  }
  #pragma unroll
  for (int o = 1; o < 16; o <<= 1) {
    rs0 += __shfl_xor(rs0, o);
    rs1 += __shfl_xor(rs1, o);
    rs2 += __shfl_xor(rs2, o);
    rs3 += __shfl_xor(rs3, o);
  }
  if (m == 0) {
    float* dst = &sumexp[b0 + w*16 + q*4];
    atomicAdd(&dst[0], rs0);
    atomicAdd(&dst[1], rs1);
    atomicAdd(&dst[2], rs2);
    atomicAdd(&dst[3], rs3);
  }
}

// ---------------- per-sample terms (bf16 E_sum tables); 3 atomics/block ----------------
__global__ __launch_bounds__(256) void perb_kernel(const int* __restrict__ uids, const int* __restrict__ iids,
    const int* __restrict__ pos, const int* __restrict__ neg,
    const float* __restrict__ Ggu, const float* __restrict__ Gdi,
    const ushort* __restrict__ Egs_b, const ushort* __restrict__ Eds_b,
    const float* __restrict__ seg, const float* __restrict__ sed,
    float* __restrict__ accs) {
  __shared__ float lsum[3][4];
  int t = threadIdx.x, lane = t & 63, w = t >> 6;
  int b = blockIdx.x*4 + w;
  int u = uids[b], it = iids[b], p = pos[b], ng = neg[b];
  float egu = bf2f(Egs_b[(size_t)u*DIM + lane]);
  float d1 = Ggu[(size_t)b*DIM + lane]*egu;
  float d2 = Gdi[(size_t)b*DIM + lane]*bf2f(Eds_b[(size_t)it*DIM + lane]);
  float d3 = egu*bf2f(Eds_b[(size_t)p*DIM + lane]);
  float d4 = egu*bf2f(Eds_b[(size_t)ng*DIM + lane]);
  #pragma unroll
  for (int o = 32; o > 0; o >>= 1) {
    d1 += __shfl_xor(d1, o);
    d2 += __shfl_xor(d2, o);
    d3 += __shfl_xor(d3, o);
    d4 += __shfl_xor(d4, o);
  }
  if (lane == 0) {
    float pterm = fminf(fmaxf(d1*INVT, -5.f), 5.f) + fminf(fmaxf(d2*INVT, -5.f), 5.f);
    float diff = d3 - d4;
    lsum[0][w] = pterm;
    lsum[1][w] = log1pf(expf(-diff));
    lsum[2][w] = logf(seg[b] + 1e-8f) + logf(sed[b] + 1e-8f);
  }
  __syncthreads();
  if (t < 3) atomicAdd(&accs[t], lsum[t][0] + lsum[t][1] + lsum[t][2] + lsum[t][3]);
}

__global__ void final_kernel(const float* __restrict__ accs, float* __restrict__ out) {
  float posm = accs[0]*(1.f/BSZ);
  float lr   = accs[1]*(1.f/BSZ);
  float negm = accs[2]*(1.f/BSZ);
  float reg  = 1e-7f*accs[3];
  float l1ls = 0.2f*(negm - posm);
  out[0] = lr + l1ls + reg;
  out[1] = lr;
  out[2] = l1ls;
}

extern "C" void kernel_launch(void* const* d_in, const int* in_sizes, int n_in,
                              void* d_out, int out_size, void* d_ws, size_t ws_size,
                              hipStream_t stream) {
  (void)in_sizes; (void)n_in; (void)out_size;
  const int*   uids = (const int*)d_in[0];
  const int*   iids = (const int*)d_in[1];
  const int*   pos  = (const int*)d_in[2];
  const int*   neg  = (const int*)d_in[3];
  const float* Eg0  = (const float*)d_in[4];
  const float* Ed0  = (const float*)d_in[5];
  const int*   rows = (const int*)d_in[6];
  const int*   cols = (const int*)d_in[7];
  const float* vals = (const float*)d_in[8];
  const float* gms  = (const float*)d_in[9];
  const float* vms  = (const float*)d_in[10];
  const float* ut   = (const float*)d_in[11];
  const float* vt   = (const float*)d_in[12];
  const float* drop = (const float*)d_in[13];
  float* out = (float*)d_out;

  float* ws = (float*)d_ws;
  const size_t ED = (size_t)N_Gc*DIM;  // 3.2M
  float* Zg0  = ws;            // [ED] fp32 Z layer0 r-side; earlier: stage_r (NNZ uint2 = ED floats)
  float* Zd0  = Zg0 + ED;      // [ED] fp32 Z layer0 c-side
  float* REG1 = Zd0 + ED;      // [ED] : stage_c -> (Eg0_b,Ed0_b) -> (Egs_b,Eds_b)
  float* REG2 = REG1 + ED;     // [ED] : (Zg0_b, Zd0_b)
  int* ptr_r = (int*)(REG2 + ED);
  int* ptr_c = ptr_r + (N_Gc + 1);
  int* bcnt_r = ptr_c + (N_Dc + 1);        // zeroed zone A
  int* bcnt_c = bcnt_r + NBK;              // zone A end
  int* bptr_r = bcnt_c + NBK;
  int* bptr_c = bptr_r + (NBK + 1);
  int* gcur_r = bptr_c + (NBK + 1);
  int* gcur_c = gcur_r + NBK*CPAD;
  ushort* fcol_r = (ushort*)(gcur_c + NBK*CPAD);
  float* fw_r0  = (float*)(fcol_r + NNZc);
  float* fw_r1  = fw_r0 + NNZc;
  ushort* fcol_c = (ushort*)(fw_r1 + NNZc);
  float* fw_c0  = (float*)(fcol_c + NNZc);
  float* fw_c1  = fw_c0 + NNZc;
  float* Ggu = fw_c1 + NNZc;
  float* Gdi = Ggu + (size_t)BSZ*DIM;
  ushort* Ggu_b = (ushort*)(Gdi + (size_t)BSZ*DIM);
  ushort* Gdi_b = Ggu_b + (size_t)BSZ*DIM;
  float* Mg  = (float*)(Gdi_b + (size_t)BSZ*DIM);  // zeroed zone B
  float* Md  = Mg + RNK*DIM;
  float* seg = Md + RNK*DIM;
  float* sed = seg + BSZ;
  float* accs = sed + BSZ;              // 16 floats

  // overlays (lifetimes are disjoint on the serial stream):
  uint2* stage_r = (uint2*)Zg0;                 // phaseA..phaseB
  uint2* stage_c = (uint2*)REG1;                // phaseA..phaseB
  ushort* Eg0_b = (ushort*)REG1;                // conv..layer0
  ushort* Ed0_b = Eg0_b + ED;
  ushort* Egs_b = (ushort*)REG1;                // layer1..end (overwrites dead Eg0_b)
  ushort* Eds_b = Egs_b + ED;
  ushort* Zg0_b = (ushort*)REG2;                // layer0..layer1
  ushort* Zd0_b = Zg0_b + ED;

  size_t need = ((char*)(accs + 16)) - ((char*)d_ws);
  if (ws_size < need) return;

  hipMemsetAsync(bcnt_r, 0, sizeof(int)*(2*NBK), stream);
  hipMemsetAsync(Mg, 0, sizeof(float)*(2*RNK*DIM + 2*BSZ + 16), stream);

  hist2_kernel<<<NNZc/EPB, 256, 0, stream>>>(rows, cols, bcnt_r, bcnt_c);
  cscan_kernel<<<2, 1024, 0, stream>>>(bcnt_r, bcnt_c, gcur_r, gcur_c, bptr_r, bptr_c);
  phaseA_kernel<<<NNZc/EPB, 256, 0, stream>>>(rows, cols, vals, drop, gcur_r, gcur_c, stage_r, stage_c);
  phaseB_kernel<<<NBK, 256, 0, stream>>>(bptr_r, ptr_r, stage_r, fcol_r, fw_r0, fw_r1, N_Gc);
  phaseB_kernel<<<NBK, 256, 0, stream>>>(bptr_c, ptr_c, stage_c, fcol_c, fw_c0, fw_c1, N_Dc);

  // bf16 copies of the layer-0 gather tables (stage_c now dead) + fused L2-reg sum-of-squares
  int n4 = (int)(ED/4);
  convsq_kernel<<<1024, 256, 0, stream>>>((const float4*)Eg0, (ushort4*)Eg0_b, n4, accs + 3);
  convsq_kernel<<<1024, 256, 0, stream>>>((const float4*)Ed0, (ushort4*)Ed0_b, n4, accs + 3);

  int spmm_blocks = (N_Gc + 3)/4;
  // layer 0: Zg0 = A0 @ Ed0 ; Zd0 = A0^T @ Eg0  (bf16 gathers, fp32 + bf16 outputs)
  spmm_l0_kernel<<<spmm_blocks, 256, 0, stream>>>(ptr_r, fcol_r, fw_r0, Ed0_b, Zg0, Zg0_b, N_Gc);
  spmm_l0_kernel<<<spmm_blocks, 256, 0, stream>>>(ptr_c, fcol_c, fw_c0, Eg0_b, Zd0, Zd0_b, N_Dc);
  // layer 1 fused: Egs = Eg0 + Zg0 + A1 @ Zd0 -> bf16 only ; Eds likewise
  spmm_l1_kernel<<<spmm_blocks, 256, 0, stream>>>(ptr_r, fcol_r, fw_r1, Zd0_b, Eg0, Zg0, Egs_b, N_Gc);
  spmm_l1_kernel<<<spmm_blocks, 256, 0, stream>>>(ptr_c, fcol_c, fw_c1, Zg0_b, Ed0, Zd0, Eds_b, N_Dc);

  // Mg = vt @ (Ed0 + Zd0) ; Md = ut @ (Eg0 + Zg0)
  matred_kernel<<<64, 256, 0, stream>>>(vt, Ed0, Zd0, Mg, N_Dc);
  matred_kernel<<<64, 256, 0, stream>>>(ut, Eg0, Zg0, Md, N_Gc);

  gsmall_kernel<<<BSZ/4, 256, 0, stream>>>(uids, Eg0, gms, Mg, Ggu, Ggu_b);
  gsmall_kernel<<<BSZ/4, 256, 0, stream>>>(iids, Ed0, vms, Md, Gdi, Gdi_b);

  lse_mfma_kernel<<<32*NSL, 256, 0, stream>>>(Ggu_b, Egs_b, N_Gc, seg);
  lse_mfma_kernel<<<32*NSL, 256, 0, stream>>>(Gdi_b, Eds_b, N_Dc, sed);

  perb_kernel<<<BSZ/4, 256, 0, stream>>>(uids, iids, pos, neg, Ggu, Gdi, Egs_b, Eds_b, seg, sed, accs);
  final_kernel<<<1, 1, 0, stream>>>(accs, out);
}

// Round 8
// 675.035 us; speedup vs baseline: 1.6513x; 1.1128x over previous
//
#include <hip/hip_runtime.h>
#include <hip/hip_bf16.h>
#include <math.h>

#define N_Gc 50000
#define N_Dc 50000
#define DIM 64
#define RNK 32
#define NNZc 1600000
#define BSZ 2048
#define KEEPV (1.0f/0.9f)
#define INVT 5.0f
#define NBK 782      // (50000+63)/64 buckets of 64 rows
#define CPAD 16      // ints per cursor (one 64B line each)
#define NSL 24       // j-slices for lse grid
#define EPB 8000     // edges per block (hist2 + phaseA): NNZ/EPB = 200 blocks
#define MCH 256      // matred i-chunk per block
#define MBLK 196     // ceil(50000/256)

typedef __attribute__((ext_vector_type(8))) short bfrag;
typedef __attribute__((ext_vector_type(4))) float f32x4;

__device__ inline ushort f2bf(float f) {
  union { float f; unsigned int u; } v; v.f = f;
  unsigned int r = (v.u + 0x7fffu + ((v.u >> 16) & 1u)) >> 16;
  return (ushort)r;
}
__device__ inline float bf2f(ushort u) {
  union { unsigned int i; float f; } v; v.i = ((unsigned int)u) << 16;
  return v.f;
}

// ---------------- hist2: LDS-privatized per-bucket counts ----------------
__global__ __launch_bounds__(256) void hist2_kernel(const int* __restrict__ rows, const int* __restrict__ cols,
                                                    int* __restrict__ bcnt_r, int* __restrict__ bcnt_c) {
  __shared__ int lh_r[NBK];
  __shared__ int lh_c[NBK];
  int t = threadIdx.x;
  for (int j = t; j < NBK; j += 256) { lh_r[j] = 0; lh_c[j] = 0; }
  __syncthreads();
  int e0 = blockIdx.x*EPB;
  for (int i = e0 + t; i < e0 + EPB; i += 256) {
    atomicAdd(&lh_r[rows[i] >> 6], 1);
    atomicAdd(&lh_c[cols[i] >> 6], 1);
  }
  __syncthreads();
  for (int j = t; j < NBK; j += 256) {
    int vr = lh_r[j]; if (vr) atomicAdd(&bcnt_r[j], vr);
    int vc = lh_c[j]; if (vc) atomicAdd(&bcnt_c[j], vc);
  }
}

// ---------------- cscan: prefix over bucket counts -> bucket bases + cursors ----------------
__global__ __launch_bounds__(1024) void cscan_kernel(const int* __restrict__ bcnt_r, const int* __restrict__ bcnt_c,
                                                     int* __restrict__ gcur_r, int* __restrict__ gcur_c,
                                                     int* __restrict__ bptr_r, int* __restrict__ bptr_c) {
  const int* cnt = blockIdx.x ? bcnt_c : bcnt_r;
  int* gcur = blockIdx.x ? gcur_c : gcur_r;
  int* bptr = blockIdx.x ? bptr_c : bptr_r;
  __shared__ int wsum[16];
  int t = threadIdx.x, lane = t & 63, w = t >> 6;
  int v = (t < NBK) ? cnt[t] : 0;
  int x = v;
  #pragma unroll
  for (int o = 1; o < 64; o <<= 1) { int y = __shfl_up(x, o); if (lane >= o) x += y; }
  if (lane == 63) wsum[w] = x;
  __syncthreads();
  if (t < 16) {
    int s = wsum[t];
    #pragma unroll
    for (int o = 1; o < 16; o <<= 1) { int y = __shfl_up(s, o); if (t >= o) s += y; }
    wsum[t] = s;
  }
  __syncthreads();
  int ex = ((w == 0) ? 0 : wsum[w-1]) + (x - v);
  if (t < NBK) { gcur[t*CPAD] = ex; bptr[t] = ex; }
  if (t == 0) bptr[NBK] = wsum[15];
}

// ---------------- phase A: block-local reserve + contiguous-run scatter ----------------
__global__ __launch_bounds__(256) void phaseA_kernel(const int* __restrict__ rows, const int* __restrict__ cols,
    const float* __restrict__ vals, const float* __restrict__ drop,
    int* __restrict__ gcur_r, int* __restrict__ gcur_c,
    uint2* __restrict__ stage_r, uint2* __restrict__ stage_c) {
  __shared__ int cnt_r[NBK], cnt_c[NBK];
  __shared__ int base_r[NBK], base_c[NBK];
  int t = threadIdx.x;
  for (int j = t; j < NBK; j += 256) { cnt_r[j] = 0; cnt_c[j] = 0; }
  __syncthreads();
  int e0 = blockIdx.x*EPB;
  for (int i = e0 + t; i < e0 + EPB; i += 256) {
    atomicAdd(&cnt_r[rows[i] >> 6], 1);
    atomicAdd(&cnt_c[cols[i] >> 6], 1);
  }
  __syncthreads();
  for (int j = t; j < NBK; j += 256) {
    int c = cnt_r[j]; base_r[j] = c ? atomicAdd(&gcur_r[j*CPAD], c) : 0; cnt_r[j] = 0;
    c = cnt_c[j];     base_c[j] = c ? atomicAdd(&gcur_c[j*CPAD], c) : 0; cnt_c[j] = 0;
  }
  __syncthreads();
  for (int i = e0 + t; i < e0 + EPB; i += 256) {
    int r = rows[i], c = cols[i];
    unsigned int vb = __float_as_uint(vals[i]);
    unsigned int dr0 = (drop[i] > 0.1f) ? (1u<<22) : 0u;
    unsigned int dc0 = (drop[(size_t)NNZc + i] > 0.1f) ? (1u<<22) : 0u;
    unsigned int dr1 = (drop[2*(size_t)NNZc + i] > 0.1f) ? (1u<<23) : 0u;
    unsigned int dc1 = (drop[3*(size_t)NNZc + i] > 0.1f) ? (1u<<23) : 0u;
    int br = r >> 6, bc = c >> 6;
    int p = base_r[br] + atomicAdd(&cnt_r[br], 1);
    stage_r[p] = make_uint2((unsigned int)c | ((unsigned int)(r & 63) << 16) | dr0 | dr1, vb);
    int q = base_c[bc] + atomicAdd(&cnt_c[bc], 1);
    stage_c[q] = make_uint2((unsigned int)r | ((unsigned int)(c & 63) << 16) | dc0 | dc1, vb);
  }
}

// ---------------- phase B: per-bucket row-count + prefix + place; writes CSR ptr ----------------
__global__ __launch_bounds__(256) void phaseB_kernel(const int* __restrict__ bptr, int* __restrict__ ptrout,
    const uint2* __restrict__ stage, ushort* __restrict__ fcol,
    float* __restrict__ fw0, float* __restrict__ fw1, int n) {
  __shared__ int cnt[64];
  __shared__ int pos[64];
  int t = threadIdx.x, b = blockIdx.x;
  int base_row = b*64;
  int base = bptr[b], endp = bptr[b+1];
  if (t < 64) cnt[t] = 0;
  __syncthreads();
  for (int k = base + t; k < endp; k += 256)
    atomicAdd(&cnt[(stage[k].x >> 16) & 63], 1);
  __syncthreads();
  if (t < 64) {
    int c = cnt[t], x = c;
    #pragma unroll
    for (int o = 1; o < 64; o <<= 1) { int y = __shfl_up(x, o); if (t >= o) x += y; }
    int excl = x - c;
    pos[t] = excl;
    int rr = base_row + t;
    if (rr <= n) ptrout[rr] = base + excl;
  }
  __syncthreads();
  for (int k = base + t; k < endp; k += 256) {
    uint2 rec = stage[k];
    int rel = (rec.x >> 16) & 63;
    int p = base + atomicAdd(&pos[rel], 1);
    float v = __uint_as_float(rec.y);
    fcol[p] = (ushort)(rec.x & 0xffffu);
    fw0[p] = (rec.x & (1u<<22)) ? v*KEEPV : 0.f;
    fw1[p] = (rec.x & (1u<<23)) ? v*KEEPV : 0.f;
  }
}

// ---------------- layer-0 SpMM: bf16 gather -> fp32 Z + bf16 Z copy ----------------
__global__ __launch_bounds__(256) void spmm_l0_kernel(const int* __restrict__ ptr,
    const ushort* __restrict__ fcol, const float* __restrict__ fw,
    const ushort* __restrict__ Eb, float* __restrict__ Z, ushort* __restrict__ Zb, int nrows) {
  int lane = threadIdx.x & 63;
  int row = blockIdx.x*4 + (threadIdx.x >> 6);
  if (row >= nrows) return;
  int k = ptr[row], end = ptr[row+1];
  float acc = 0.f;
  for (; k + 8 <= end; k += 8) {
    int cc[8]; float ww[8]; float gg[8];
    #pragma unroll
    for (int u = 0; u < 8; u++) { cc[u] = fcol[k+u]; ww[u] = fw[k+u]; }
    #pragma unroll
    for (int u = 0; u < 8; u++) gg[u] = bf2f(Eb[(size_t)cc[u]*DIM + lane]);
    #pragma unroll
    for (int u = 0; u < 8; u++) acc += ww[u]*gg[u];
  }
  for (; k < end; k++)
    acc += fw[k]*bf2f(Eb[(size_t)fcol[k]*DIM + lane]);
  size_t o = (size_t)row*DIM + lane;
  Z[o] = acc;
  Zb[o] = f2bf(acc);
}

// ---------------- layer-1 SpMM fused with E_sum: bf16 gather + fp32 adds -> bf16 out ----------------
__global__ __launch_bounds__(256) void spmm_l1_kernel(const int* __restrict__ ptr,
    const ushort* __restrict__ fcol, const float* __restrict__ fw,
    const ushort* __restrict__ Zb, const float* __restrict__ addA, const float* __restrict__ addB,
    ushort* __restrict__ Eout, int nrows) {
  int lane = threadIdx.x & 63;
  int row = blockIdx.x*4 + (threadIdx.x >> 6);
  if (row >= nrows) return;
  int k = ptr[row], end = ptr[row+1];
  float acc = 0.f;
  for (; k + 8 <= end; k += 8) {
    int cc[8]; float ww[8]; float gg[8];
    #pragma unroll
    for (int u = 0; u < 8; u++) { cc[u] = fcol[k+u]; ww[u] = fw[k+u]; }
    #pragma unroll
    for (int u = 0; u < 8; u++) gg[u] = bf2f(Zb[(size_t)cc[u]*DIM + lane]);
    #pragma unroll
    for (int u = 0; u < 8; u++) acc += ww[u]*gg[u];
  }
  for (; k < end; k++)
    acc += fw[k]*bf2f(Zb[(size_t)fcol[k]*DIM + lane]);
  size_t o = (size_t)row*DIM + lane;
  acc += addA[o] + addB[o];
  Eout[o] = f2bf(acc);
}

// ---------------- matred stage 1: per-chunk partial M = vrow @ (E0+Z0) ----------------
// block = one 256-i chunk; vrow chunk staged coalesced in LDS; ds_read_b128 broadcasts.
__global__ __launch_bounds__(256) void matred2_kernel(const float* __restrict__ vrow,
    const float* __restrict__ E0, const float* __restrict__ Z0,
    float* __restrict__ Mpart, int n) {
  __shared__ float vs[RNK*MCH];     // 32KB, [r][i]
  __shared__ float part[RNK*DIM];   // 8KB
  int t = threadIdx.x, lane = t & 63, w = t >> 6;
  int ci0 = blockIdx.x*MCH;
  int cnt = min(MCH, n - ci0);
  for (int idx = t; idx < RNK*DIM; idx += 256) part[idx] = 0.f;
  for (int idx = t; idx < RNK*MCH; idx += 256) {
    int r = idx >> 8, i = idx & (MCH-1);
    vs[idx] = (i < cnt) ? vrow[(size_t)r*n + ci0 + i] : 0.f;
  }
  __syncthreads();
  float acc[RNK];
  #pragma unroll
  for (int r = 0; r < RNK; r++) acc[r] = 0.f;
  int iw0 = w*64;
  for (int ii = 0; ii < 64; ii += 4) {
    int i = iw0 + ii;
    int gi = ci0 + i;
    float x0 = 0.f, x1 = 0.f, x2 = 0.f, x3 = 0.f;
    if (i + 3 < cnt) {
      x0 = E0[(size_t)(gi+0)*DIM + lane] + Z0[(size_t)(gi+0)*DIM + lane];
      x1 = E0[(size_t)(gi+1)*DIM + lane] + Z0[(size_t)(gi+1)*DIM + lane];
      x2 = E0[(size_t)(gi+2)*DIM + lane] + Z0[(size_t)(gi+2)*DIM + lane];
      x3 = E0[(size_t)(gi+3)*DIM + lane] + Z0[(size_t)(gi+3)*DIM + lane];
    } else {
      if (i+0 < cnt) x0 = E0[(size_t)(gi+0)*DIM + lane] + Z0[(size_t)(gi+0)*DIM + lane];
      if (i+1 < cnt) x1 = E0[(size_t)(gi+1)*DIM + lane] + Z0[(size_t)(gi+1)*DIM + lane];
      if (i+2 < cnt) x2 = E0[(size_t)(gi+2)*DIM + lane] + Z0[(size_t)(gi+2)*DIM + lane];
      if (i+3 < cnt) x3 = E0[(size_t)(gi+3)*DIM + lane] + Z0[(size_t)(gi+3)*DIM + lane];
    }
    #pragma unroll
    for (int r = 0; r < RNK; r++) {
      float4 v4 = *(const float4*)&vs[r*MCH + i];   // wave-uniform broadcast
      acc[r] += v4.x*x0 + v4.y*x1 + v4.z*x2 + v4.w*x3;
    }
  }
  #pragma unroll
  for (int r = 0; r < RNK; r++) atomicAdd(&part[r*DIM + lane], acc[r]);
  __syncthreads();
  float* dst = Mpart + (size_t)blockIdx.x*(RNK*DIM);
  for (int idx = t; idx < RNK*DIM; idx += 256) dst[idx] = part[idx];
}

// ---------------- matred stage 2: reduce partials ----------------
__global__ __launch_bounds__(256) void mreduce_kernel(const float* __restrict__ Mpart,
    float* __restrict__ M, int nblk) {
  int idx = blockIdx.x*256 + threadIdx.x;
  if (idx < RNK*DIM) {
    float s = 0.f;
    for (int b = 0; b < nblk; b++) s += Mpart[(size_t)b*(RNK*DIM) + idx];
    M[idx] = s;
  }
}

// ---------------- G rows at sampled ids (fp32 + bf16 out) ----------------
__global__ __launch_bounds__(256) void gsmall_kernel(const int* __restrict__ ids,
    const float* __restrict__ E0, const float* __restrict__ mul, const float* __restrict__ M,
    float* __restrict__ out, ushort* __restrict__ outb) {
  __shared__ float Ms[RNK*DIM];
  int t = threadIdx.x;
  for (int i = t; i < RNK*DIM; i += 256) Ms[i] = M[i];
  __syncthreads();
  int b = blockIdx.x*4 + (t >> 6), lane = t & 63;
  int u = ids[b];
  float a = E0[(size_t)u*DIM + lane];
  #pragma unroll
  for (int r = 0; r < RNK; r++) a += mul[(size_t)u*RNK + r]*Ms[r*DIM + lane];
  out[(size_t)b*DIM + lane] = a;
  outb[(size_t)b*DIM + lane] = f2bf(a);
}

// ---------------- fp32 -> bf16 conversion fused with sum-of-squares (1 atomic/block) ----------------
__global__ __launch_bounds__(256) void convsq_kernel(const float4* __restrict__ in,
    ushort4* __restrict__ out, int n4, float* __restrict__ acc) {
  __shared__ float ls[4];
  int t = threadIdx.x;
  int idx = blockIdx.x*256 + t;
  int stride = gridDim.x*256;
  float s = 0.f;
  for (int i = idx; i < n4; i += stride) {
    float4 v = in[i];
    ushort4 o;
    o.x = f2bf(v.x); o.y = f2bf(v.y); o.z = f2bf(v.z); o.w = f2bf(v.w);
    out[i] = o;
    s += v.x*v.x + v.y*v.y + v.z*v.z + v.w*v.w;
  }
  #pragma unroll
  for (int o = 32; o > 0; o >>= 1) s += __shfl_xor(s, o);
  if ((t & 63) == 0) ls[t >> 6] = s;
  __syncthreads();
  if (t == 0) atomicAdd(acc, ls[0] + ls[1] + ls[2] + ls[3]);
}

// ---------------- bf16 MFMA fused GEMM + exp + row-sum ----------------
__global__ __launch_bounds__(256) void lse_mfma_kernel(const ushort* __restrict__ A,
    const ushort* __restrict__ X, int nj, float* __restrict__ sumexp) {
  __shared__ __align__(16) ushort Xs[64*68];
  int t = threadIdx.x, lane = t & 63, w = t >> 6;
  int bt = blockIdx.x & 31, js = blockIdx.x >> 5;
  int b0 = bt*64;
  int m = lane & 15, q = lane >> 4;
  const ushort* Arow = A + (size_t)(b0 + w*16 + m)*DIM + q*8;
  bfrag a0 = *(const bfrag*)(Arow);
  bfrag a1 = *(const bfrag*)(Arow + 32);
  float rs0 = 0.f, rs1 = 0.f, rs2 = 0.f, rs3 = 0.f;
  int njt = (nj + 63) >> 6;
  for (int jt = js; jt < njt; jt += NSL) {
    int j0 = jt << 6;
    __syncthreads();
    for (int c = t; c < 512; c += 256) {
      int r = c >> 3, k8 = (c & 7) << 3;
      int j = j0 + r;
      ushort4 v0 = {0,0,0,0}, v1 = {0,0,0,0};
      if (j < nj) {
        const ushort4* src = (const ushort4*)(X + (size_t)j*DIM + k8);
        v0 = src[0]; v1 = src[1];
      }
      *(ushort4*)&Xs[r*68 + k8]     = v0;
      *(ushort4*)&Xs[r*68 + k8 + 4] = v1;
    }
    __syncthreads();
    #pragma unroll
    for (int jq = 0; jq < 4; jq++) {
      int jr = jq*16 + m;
      union { bfrag f; uint2 u2[2]; } B0, B1;
      B0.u2[0] = *(const uint2*)&Xs[jr*68 + q*8];
      B0.u2[1] = *(const uint2*)&Xs[jr*68 + q*8 + 4];
      B1.u2[0] = *(const uint2*)&Xs[jr*68 + 32 + q*8];
      B1.u2[1] = *(const uint2*)&Xs[jr*68 + 32 + q*8 + 4];
      f32x4 acc = {0.f, 0.f, 0.f, 0.f};
      acc = __builtin_amdgcn_mfma_f32_16x16x32_bf16(a0, B0.f, acc, 0, 0, 0);
      acc = __builtin_amdgcn_mfma_f32_16x16x32_bf16(a1, B1.f, acc, 0, 0, 0);
      int jg = j0 + jr;
      if (jg < nj) {
        rs0 += __expf(acc[0]*INVT);
        rs1 += __expf(acc[1]*INVT);
        rs2 += __expf(acc[2]*INVT);
        rs3 += __expf(acc[3]*INVT);
      }
    }
  }
  #pragma unroll
  for (int o = 1; o < 16; o <<= 1) {
    rs0 += __shfl_xor(rs0, o);
    rs1 += __shfl_xor(rs1, o);
    rs2 += __shfl_xor(rs2, o);
    rs3 += __shfl_xor(rs3, o);
  }
  if (m == 0) {
    float* dst = &sumexp[b0 + w*16 + q*4];
    atomicAdd(&dst[0], rs0);
    atomicAdd(&dst[1], rs1);
    atomicAdd(&dst[2], rs2);
    atomicAdd(&dst[3], rs3);
  }
}

// ---------------- per-sample terms (bf16 E_sum tables); 3 atomics/block ----------------
__global__ __launch_bounds__(256) void perb_kernel(const int* __restrict__ uids, const int* __restrict__ iids,
    const int* __restrict__ pos, const int* __restrict__ neg,
    const float* __restrict__ Ggu, const float* __restrict__ Gdi,
    const ushort* __restrict__ Egs_b, const ushort* __restrict__ Eds_b,
    const float* __restrict__ seg, const float* __restrict__ sed,
    float* __restrict__ accs) {
  __shared__ float lsum[3][4];
  int t = threadIdx.x, lane = t & 63, w = t >> 6;
  int b = blockIdx.x*4 + w;
  int u = uids[b], it = iids[b], p = pos[b], ng = neg[b];
  float egu = bf2f(Egs_b[(size_t)u*DIM + lane]);
  float d1 = Ggu[(size_t)b*DIM + lane]*egu;
  float d2 = Gdi[(size_t)b*DIM + lane]*bf2f(Eds_b[(size_t)it*DIM + lane]);
  float d3 = egu*bf2f(Eds_b[(size_t)p*DIM + lane]);
  float d4 = egu*bf2f(Eds_b[(size_t)ng*DIM + lane]);
  #pragma unroll
  for (int o = 32; o > 0; o >>= 1) {
    d1 += __shfl_xor(d1, o);
    d2 += __shfl_xor(d2, o);
    d3 += __shfl_xor(d3, o);
    d4 += __shfl_xor(d4, o);
  }
  if (lane == 0) {
    float pterm = fminf(fmaxf(d1*INVT, -5.f), 5.f) + fminf(fmaxf(d2*INVT, -5.f), 5.f);
    float diff = d3 - d4;
    lsum[0][w] = pterm;
    lsum[1][w] = log1pf(expf(-diff));
    lsum[2][w] = logf(seg[b] + 1e-8f) + logf(sed[b] + 1e-8f);
  }
  __syncthreads();
  if (t < 3) atomicAdd(&accs[t], lsum[t][0] + lsum[t][1] + lsum[t][2] + lsum[t][3]);
}

__global__ void final_kernel(const float* __restrict__ accs, float* __restrict__ out) {
  float posm = accs[0]*(1.f/BSZ);
  float lr   = accs[1]*(1.f/BSZ);
  float negm = accs[2]*(1.f/BSZ);
  float reg  = 1e-7f*accs[3];
  float l1ls = 0.2f*(negm - posm);
  out[0] = lr + l1ls + reg;
  out[1] = lr;
  out[2] = l1ls;
}

extern "C" void kernel_launch(void* const* d_in, const int* in_sizes, int n_in,
                              void* d_out, int out_size, void* d_ws, size_t ws_size,
                              hipStream_t stream) {
  (void)in_sizes; (void)n_in; (void)out_size;
  const int*   uids = (const int*)d_in[0];
  const int*   iids = (const int*)d_in[1];
  const int*   pos  = (const int*)d_in[2];
  const int*   neg  = (const int*)d_in[3];
  const float* Eg0  = (const float*)d_in[4];
  const float* Ed0  = (const float*)d_in[5];
  const int*   rows = (const int*)d_in[6];
  const int*   cols = (const int*)d_in[7];
  const float* vals = (const float*)d_in[8];
  const float* gms  = (const float*)d_in[9];
  const float* vms  = (const float*)d_in[10];
  const float* ut   = (const float*)d_in[11];
  const float* vt   = (const float*)d_in[12];
  const float* drop = (const float*)d_in[13];
  float* out = (float*)d_out;

  float* ws = (float*)d_ws;
  const size_t ED = (size_t)N_Gc*DIM;  // 3.2M
  float* Zg0  = ws;            // [ED] fp32 Z layer0 r-side; earlier: stage_r (NNZ uint2 = ED floats)
  float* Zd0  = Zg0 + ED;      // [ED] fp32 Z layer0 c-side
  float* REG1 = Zd0 + ED;      // [ED] : stage_c -> (Eg0_b,Ed0_b) -> (Egs_b,Eds_b)
  float* REG2 = REG1 + ED;     // [ED] : (Zg0_b, Zd0_b)
  int* ptr_r = (int*)(REG2 + ED);
  int* ptr_c = ptr_r + (N_Gc + 1);
  int* bcnt_r = ptr_c + (N_Dc + 1);        // zeroed zone A
  int* bcnt_c = bcnt_r + NBK;              // zone A end
  int* bptr_r = bcnt_c + NBK;
  int* bptr_c = bptr_r + (NBK + 1);
  int* gcur_r = bptr_c + (NBK + 1);
  int* gcur_c = gcur_r + NBK*CPAD;
  ushort* fcol_r = (ushort*)(gcur_c + NBK*CPAD);
  float* fw_r0  = (float*)(fcol_r + NNZc);
  float* fw_r1  = fw_r0 + NNZc;
  ushort* fcol_c = (ushort*)(fw_r1 + NNZc);
  float* fw_c0  = (float*)(fcol_c + NNZc);
  float* fw_c1  = fw_c0 + NNZc;
  float* Ggu = fw_c1 + NNZc;
  float* Gdi = Ggu + (size_t)BSZ*DIM;
  ushort* Ggu_b = (ushort*)(Gdi + (size_t)BSZ*DIM);
  ushort* Gdi_b = Ggu_b + (size_t)BSZ*DIM;
  float* Mg  = (float*)(Gdi_b + (size_t)BSZ*DIM);  // zeroed zone B
  float* Md  = Mg + RNK*DIM;
  float* seg = Md + RNK*DIM;
  float* sed = seg + BSZ;
  float* accs = sed + BSZ;              // 16 floats
  float* MpG = accs + 16;               // matred partials: MBLK*2048 each
  float* MpD = MpG + (size_t)MBLK*RNK*DIM;

  // overlays (lifetimes are disjoint on the serial stream):
  uint2* stage_r = (uint2*)Zg0;                 // phaseA..phaseB
  uint2* stage_c = (uint2*)REG1;                // phaseA..phaseB
  ushort* Eg0_b = (ushort*)REG1;                // conv..layer0
  ushort* Ed0_b = Eg0_b + ED;
  ushort* Egs_b = (ushort*)REG1;                // layer1..end (overwrites dead Eg0_b)
  ushort* Eds_b = Egs_b + ED;
  ushort* Zg0_b = (ushort*)REG2;                // layer0..layer1
  ushort* Zd0_b = Zg0_b + ED;

  size_t need = ((char*)(MpD + (size_t)MBLK*RNK*DIM)) - ((char*)d_ws);
  if (ws_size < need) return;

  hipMemsetAsync(bcnt_r, 0, sizeof(int)*(2*NBK), stream);
  hipMemsetAsync(Mg, 0, sizeof(float)*(2*RNK*DIM + 2*BSZ + 16), stream);

  hist2_kernel<<<NNZc/EPB, 256, 0, stream>>>(rows, cols, bcnt_r, bcnt_c);
  cscan_kernel<<<2, 1024, 0, stream>>>(bcnt_r, bcnt_c, gcur_r, gcur_c, bptr_r, bptr_c);
  phaseA_kernel<<<NNZc/EPB, 256, 0, stream>>>(rows, cols, vals, drop, gcur_r, gcur_c, stage_r, stage_c);
  phaseB_kernel<<<NBK, 256, 0, stream>>>(bptr_r, ptr_r, stage_r, fcol_r, fw_r0, fw_r1, N_Gc);
  phaseB_kernel<<<NBK, 256, 0, stream>>>(bptr_c, ptr_c, stage_c, fcol_c, fw_c0, fw_c1, N_Dc);

  // bf16 copies of the layer-0 gather tables (stage_c now dead) + fused L2-reg sum-of-squares
  int n4 = (int)(ED/4);
  convsq_kernel<<<1024, 256, 0, stream>>>((const float4*)Eg0, (ushort4*)Eg0_b, n4, accs + 3);
  convsq_kernel<<<1024, 256, 0, stream>>>((const float4*)Ed0, (ushort4*)Ed0_b, n4, accs + 3);

  int spmm_blocks = (N_Gc + 3)/4;
  // layer 0: Zg0 = A0 @ Ed0 ; Zd0 = A0^T @ Eg0  (bf16 gathers, fp32 + bf16 outputs)
  spmm_l0_kernel<<<spmm_blocks, 256, 0, stream>>>(ptr_r, fcol_r, fw_r0, Ed0_b, Zg0, Zg0_b, N_Gc);
  spmm_l0_kernel<<<spmm_blocks, 256, 0, stream>>>(ptr_c, fcol_c, fw_c0, Eg0_b, Zd0, Zd0_b, N_Dc);
  // layer 1 fused: Egs = Eg0 + Zg0 + A1 @ Zd0 -> bf16 only ; Eds likewise
  spmm_l1_kernel<<<spmm_blocks, 256, 0, stream>>>(ptr_r, fcol_r, fw_r1, Zd0_b, Eg0, Zg0, Egs_b, N_Gc);
  spmm_l1_kernel<<<spmm_blocks, 256, 0, stream>>>(ptr_c, fcol_c, fw_c1, Zg0_b, Ed0, Zd0, Eds_b, N_Dc);

  // Mg = vt @ (Ed0 + Zd0) ; Md = ut @ (Eg0 + Zg0)  — two-stage, no global atomics
  matred2_kernel<<<MBLK, 256, 0, stream>>>(vt, Ed0, Zd0, MpG, N_Dc);
  matred2_kernel<<<MBLK, 256, 0, stream>>>(ut, Eg0, Zg0, MpD, N_Gc);
  mreduce_kernel<<<(RNK*DIM + 255)/256, 256, 0, stream>>>(MpG, Mg, MBLK);
  mreduce_kernel<<<(RNK*DIM + 255)/256, 256, 0, stream>>>(MpD, Md, MBLK);

  gsmall_kernel<<<BSZ/4, 256, 0, stream>>>(uids, Eg0, gms, Mg, Ggu, Ggu_b);
  gsmall_kernel<<<BSZ/4, 256, 0, stream>>>(iids, Ed0, vms, Md, Gdi, Gdi_b);

  lse_mfma_kernel<<<32*NSL, 256, 0, stream>>>(Ggu_b, Egs_b, N_Gc, seg);
  lse_mfma_kernel<<<32*NSL, 256, 0, stream>>>(Gdi_b, Eds_b, N_Dc, sed);

  perb_kernel<<<BSZ/4, 256, 0, stream>>>(uids, iids, pos, neg, Ggu, Gdi, Egs_b, Eds_b, seg, sed, accs);
  final_kernel<<<1, 1, 0, stream>>>(accs, out);
}